// Round 1
// baseline (503.464 us; speedup 1.0000x reference)
//
#include <hip/hip_runtime.h>

typedef unsigned short u16;
typedef short bf16x8 __attribute__((ext_vector_type(8)));
typedef float f32x4 __attribute__((ext_vector_type(4)));
typedef unsigned int u32x4 __attribute__((ext_vector_type(4)));
typedef unsigned short u16x4 __attribute__((ext_vector_type(4)));
typedef unsigned short u16x8 __attribute__((ext_vector_type(8)));

#define LOG2E 1.4426950408889634f
#define S_LEN 2048
#define NHEAD 16
#define NKV 8
#define HD 128

__device__ __forceinline__ u16 f2bf(float f) {
  unsigned u = __builtin_bit_cast(unsigned, f);
  u = (u + 0x7FFFu + ((u >> 16) & 1u)) >> 16;
  return (u16)u;
}
__device__ __forceinline__ float bf2f(u16 h) {
  unsigned u = ((unsigned)h) << 16;
  return __builtin_bit_cast(float, u);
}

__device__ __forceinline__ void gl_lds16(const void* g, void* l) {
  __builtin_amdgcn_global_load_lds(
      (const __attribute__((address_space(1))) unsigned int*)g,
      (__attribute__((address_space(3))) unsigned int*)l, 16, 0, 0);
}

__device__ __forceinline__ float redmax16(float v) {
  v = fmaxf(v, __shfl_xor(v, 1));
  v = fmaxf(v, __shfl_xor(v, 2));
  v = fmaxf(v, __shfl_xor(v, 4));
  v = fmaxf(v, __shfl_xor(v, 8));
  return v;
}
__device__ __forceinline__ float redsum16(float v) {
  v += __shfl_xor(v, 1);
  v += __shfl_xor(v, 2);
  v += __shfl_xor(v, 4);
  v += __shfl_xor(v, 8);
  return v;
}

// ---------------- elementwise f32 -> bf16 ----------------
__global__ __launch_bounds__(256) void conv_bf16(const float* __restrict__ in,
                                                 u16* __restrict__ out, int n4) {
  int i = blockIdx.x * 256 + threadIdx.x;
  if (i >= n4) return;
  f32x4 v = *(const f32x4*)(in + (size_t)i * 4);
  u16x4 o;
#pragma unroll
  for (int j = 0; j < 4; ++j) o[j] = f2bf(v[j]);
  *(u16x4*)(out + (size_t)i * 4) = o;
}

// ---------- transpose f32 [K][N] -> bf16 [roff+n][Kout=2048] ----------
__global__ __launch_bounds__(256) void transpose_w(const float* __restrict__ in,
                                                   u16* __restrict__ out, int N,
                                                   int roff, int nx) {
  __shared__ float tile[64][65];
  int bx = blockIdx.x % nx;  // n tile
  int by = blockIdx.x / nx;  // k tile
  int k0 = by * 64, n0 = bx * 64;
  int tx = threadIdx.x & 63, ty = threadIdx.x >> 6;
#pragma unroll
  for (int p = 0; p < 16; ++p) {
    int r = p * 4 + ty;
    tile[r][tx] = in[(size_t)(k0 + r) * N + n0 + tx];
  }
  __syncthreads();
#pragma unroll
  for (int p = 0; p < 16; ++p) {
    int r = p * 4 + ty;  // output row within tile -> n
    out[(size_t)(roff + n0 + r) * 2048 + k0 + tx] = f2bf(tile[tx][r]);
  }
}

// ---------------- RoPE in-place on Q (scaled) and K ----------------
__global__ __launch_bounds__(256) void rope_qk(u16* __restrict__ q, u16* __restrict__ k,
                                               const float* __restrict__ fc,
                                               const float* __restrict__ fs) {
  const int QC = 2 * NHEAD * S_LEN * HD / 8;  // 1048576 chunks of 8 elems
  const int KC = 2 * NKV * S_LEN * HD / 8;    // 524288
  int i = blockIdx.x * 256 + threadIdx.x;
  if (i >= QC + KC) return;
  u16* base;
  float scale;
  size_t e;
  if (i < QC) {
    base = q;
    e = (size_t)i * 8;
    scale = 0.08838834764831845f;  // 1/sqrt(128)
  } else {
    base = k;
    e = (size_t)(i - QC) * 8;
    scale = 1.0f;
  }
  int d8 = (int)(e & 127);
  int s = (int)((e >> 7) & (S_LEN - 1));
  int dp0 = d8 >> 1;
  u16x8 v = *(const u16x8*)(base + e);
  u16x8 o;
#pragma unroll
  for (int p = 0; p < 4; ++p) {
    float xr = bf2f(v[2 * p]), xi = bf2f(v[2 * p + 1]);
    float c = fc[s * 64 + dp0 + p], sn = fs[s * 64 + dp0 + p];
    o[2 * p] = f2bf((xr * c - xi * sn) * scale);
    o[2 * p + 1] = f2bf((xr * sn + xi * c) * scale);
  }
  *(u16x8*)(base + e) = o;
}

// ---------------- 128x128 bf16 GEMM, B given transposed [N][K] ----------------
// EPI 0: f32 C [M][N].  EPI 1: scatter bf16 to Q/K head-major + V transposed.
template <int EPI>
__global__ __launch_bounds__(256) void gemm_bf16(
    const u16* __restrict__ A, const u16* __restrict__ Bt, float* __restrict__ Cf,
    u16* __restrict__ Qo, u16* __restrict__ Ko, u16* __restrict__ Vo, int M, int N,
    int K, int ntn) {
  __shared__ __align__(16) u16 As[128 * 32];
  __shared__ __align__(16) u16 Bs[128 * 32];

  const int t = threadIdx.x;
  const int w = t >> 6, l = t & 63, lh = l >> 4, ll = l & 15;
  const int wm = w >> 1, wn = w & 1;
  const int tm = blockIdx.x / ntn, tn = blockIdx.x % ntn;

  const u16* Ab = A + (size_t)tm * 128 * K;
  const u16* Bb = Bt + (size_t)tn * 128 * K;

  const int srow = t >> 2;
  const int scol = (t & 3) * 8;

  f32x4 acc[4][4] = {};

  for (int kt = 0; kt < K; kt += 32) {
    gl_lds16(Ab + (size_t)srow * K + kt + scol, As + t * 8);
    gl_lds16(Ab + (size_t)(64 + srow) * K + kt + scol, As + 2048 + t * 8);
    gl_lds16(Bb + (size_t)srow * K + kt + scol, Bs + t * 8);
    gl_lds16(Bb + (size_t)(64 + srow) * K + kt + scol, Bs + 2048 + t * 8);
    __syncthreads();
    bf16x8 af[4], bfr[4];
#pragma unroll
    for (int m = 0; m < 4; ++m)
      af[m] = *(const bf16x8*)(As + (wm * 64 + m * 16 + ll) * 32 + lh * 8);
#pragma unroll
    for (int n = 0; n < 4; ++n)
      bfr[n] = *(const bf16x8*)(Bs + (wn * 64 + n * 16 + ll) * 32 + lh * 8);
#pragma unroll
    for (int m = 0; m < 4; ++m)
#pragma unroll
      for (int n = 0; n < 4; ++n)
        acc[m][n] = __builtin_amdgcn_mfma_f32_16x16x32_bf16(af[m], bfr[n], acc[m][n], 0, 0, 0);
    __syncthreads();
  }

#pragma unroll
  for (int m = 0; m < 4; ++m)
#pragma unroll
    for (int n = 0; n < 4; ++n)
#pragma unroll
      for (int j = 0; j < 4; ++j) {
        int row = tm * 128 + wm * 64 + m * 16 + lh * 4 + j;
        int col = tn * 128 + wn * 64 + n * 16 + ll;
        if constexpr (EPI == 0) {
          Cf[(size_t)row * N + col] = acc[m][n][j];
        } else {
          int b = row >> 11, s = row & (S_LEN - 1);
          u16 val = f2bf(acc[m][n][j]);
          if (col < 2048) {
            int hh = col >> 7, d = col & 127;
            Qo[(((size_t)b * NHEAD + hh) * S_LEN + s) * HD + d] = val;
          } else if (col < 3072) {
            int kh = (col - 2048) >> 7, d = col & 127;
            Ko[(((size_t)b * NKV + kh) * S_LEN + s) * HD + d] = val;
          } else {
            int kh = (col - 3072) >> 7, d = col & 127;
            Vo[(((size_t)b * NKV + kh) * HD + d) * S_LEN + s] = val;
          }
        }
      }
}

// ---------------- causal GQA flash attention ----------------
// Q [B*H][S][HD] (pre-scaled), K [B*KV][S][HD], Vt [B*KV][HD][S] -> O bf16 [B*S][2048]
__global__ __launch_bounds__(256) void attn_fwd(const u16* __restrict__ Q,
                                                const u16* __restrict__ Kh,
                                                const u16* __restrict__ Vt,
                                                u16* __restrict__ O) {
  __shared__ __align__(16) u16 Ks[64 * 136];
  __shared__ __align__(16) u16 Vs[128 * 72];
  __shared__ __align__(16) u16 Ps[4][16 * 72];

  const int t = threadIdx.x;
  const int w = t >> 6, l = t & 63, lh = l >> 4, ll = l & 15;
  const int bh = blockIdx.y;
  const int qt = blockIdx.x;
  const int b = bh >> 4, h = bh & 15;
  const int bkv = b * NKV + (h >> 1);
  const int q0 = qt * 64;

  const u16* Qb = Q + (size_t)bh * S_LEN * HD;
  const u16* Kb = Kh + (size_t)bkv * S_LEN * HD;
  const u16* Vb = Vt + (size_t)bkv * HD * S_LEN;

  bf16x8 qf[4];
  const int qrow = q0 + w * 16 + ll;
#pragma unroll
  for (int c = 0; c < 4; ++c)
    qf[c] = *(const bf16x8*)(Qb + (size_t)qrow * HD + c * 32 + lh * 8);

  f32x4 accO[8] = {};
  float mrow[4], lrow[4];
#pragma unroll
  for (int j = 0; j < 4; ++j) {
    mrow[j] = -1e30f;
    lrow[j] = 0.f;
  }

  const int ntiles = q0 / 64 + 1;
  for (int tt = 0; tt < ntiles; ++tt) {
    const int kv0 = tt * 64;
    __syncthreads();  // prior tile's reads complete before restage
#pragma unroll
    for (int p = 0; p < 4; ++p) {  // K tile 64x128
      int r = p * 16 + (t >> 4);
      int c8 = (t & 15) * 8;
      *(u32x4*)(Ks + r * 136 + c8) = *(const u32x4*)(Kb + (size_t)(kv0 + r) * HD + c8);
    }
#pragma unroll
    for (int p = 0; p < 4; ++p) {  // V^T tile 128x64
      int r = p * 32 + (t >> 3);
      int c8 = (t & 7) * 8;
      *(u32x4*)(Vs + r * 72 + c8) = *(const u32x4*)(Vb + (size_t)r * S_LEN + kv0 + c8);
    }
    __syncthreads();

    // S = Q K^T  (16 q rows x 64 kv)
    f32x4 sf[4];
#pragma unroll
    for (int f = 0; f < 4; ++f) {
      sf[f] = f32x4{0.f, 0.f, 0.f, 0.f};
#pragma unroll
      for (int c = 0; c < 4; ++c) {
        bf16x8 kf = *(const bf16x8*)(Ks + (f * 16 + ll) * 136 + c * 32 + lh * 8);
        sf[f] = __builtin_amdgcn_mfma_f32_16x16x32_bf16(qf[c], kf, sf[f], 0, 0, 0);
      }
    }

    if (tt == ntiles - 1) {  // diagonal tile: causal mask
#pragma unroll
      for (int f = 0; f < 4; ++f)
#pragma unroll
        for (int j = 0; j < 4; ++j) {
          int kvg = kv0 + f * 16 + ll;
          int qg = q0 + w * 16 + lh * 4 + j;
          if (kvg > qg) sf[f][j] = -1e30f;
        }
    }

    float corr[4];
#pragma unroll
    for (int j = 0; j < 4; ++j) {
      float mx = fmaxf(fmaxf(sf[0][j], sf[1][j]), fmaxf(sf[2][j], sf[3][j]));
      mx = redmax16(mx);
      float mnew = fmaxf(mrow[j], mx);
      corr[j] = exp2f((mrow[j] - mnew) * LOG2E);
      mrow[j] = mnew;
      float rs = 0.f;
#pragma unroll
      for (int f = 0; f < 4; ++f) {
        float p = exp2f((sf[f][j] - mnew) * LOG2E);
        sf[f][j] = p;
        rs += p;
      }
      rs = redsum16(rs);
      lrow[j] = lrow[j] * corr[j] + rs;
    }
#pragma unroll
    for (int n = 0; n < 8; ++n)
#pragma unroll
      for (int j = 0; j < 4; ++j) accO[n][j] *= corr[j];

    u16* Pw = &Ps[w][0];
#pragma unroll
    for (int f = 0; f < 4; ++f)
#pragma unroll
      for (int j = 0; j < 4; ++j)
        Pw[(lh * 4 + j) * 72 + f * 16 + ll] = f2bf(sf[f][j]);

#pragma unroll
    for (int kc = 0; kc < 2; ++kc) {
      bf16x8 pf = *(const bf16x8*)(Pw + ll * 72 + kc * 32 + lh * 8);
#pragma unroll
      for (int n = 0; n < 8; ++n) {
        bf16x8 vf = *(const bf16x8*)(Vs + (n * 16 + ll) * 72 + kc * 32 + lh * 8);
        accO[n] = __builtin_amdgcn_mfma_f32_16x16x32_bf16(pf, vf, accO[n], 0, 0, 0);
      }
    }
  }

  float inv[4];
#pragma unroll
  for (int j = 0; j < 4; ++j) inv[j] = 1.0f / lrow[j];
  const size_t orow = (size_t)(b * S_LEN + q0 + w * 16 + lh * 4) * 2048 + h * HD;
#pragma unroll
  for (int n = 0; n < 8; ++n)
#pragma unroll
    for (int j = 0; j < 4; ++j)
      O[orow + (size_t)j * 2048 + n * 16 + ll] = f2bf(accO[n][j] * inv[j]);
}

extern "C" void kernel_launch(void* const* d_in, const int* in_sizes, int n_in,
                              void* d_out, int out_size, void* d_ws, size_t ws_size,
                              hipStream_t stream) {
  (void)in_sizes;
  (void)n_in;
  (void)out_size;
  (void)ws_size;
  const float* x = (const float*)d_in[0];
  const float* fc = (const float*)d_in[1];
  const float* fs = (const float*)d_in[2];
  const float* wq = (const float*)d_in[3];
  const float* wk = (const float*)d_in[4];
  const float* wv = (const float*)d_in[5];
  const float* wo = (const float*)d_in[6];
  float* out = (float*)d_out;

  char* ws = (char*)d_ws;
  u16* wcatT = (u16*)ws;                          // [4096][2048] bf16  16.78 MB
  u16* woT = (u16*)(ws + 16777216);               // [2048][2048]        8.39 MB
  u16* xo = (u16*)(ws + 25165824);                // x_bf16 then O      16.78 MB
  u16* qb = (u16*)(ws + 41943040);                // [32][2048][128]    16.78 MB
  u16* kb = (u16*)(ws + 58720256);                // [16][2048][128]     8.39 MB
  u16* vtb = (u16*)(ws + 67108864);               // [16][128][2048]     8.39 MB
  // total 75,497,472 bytes

  conv_bf16<<<8192, 256, 0, stream>>>(x, xo, 2097152);
  transpose_w<<<1024, 256, 0, stream>>>(wq, wcatT, 2048, 0, 32);
  transpose_w<<<512, 256, 0, stream>>>(wk, wcatT, 1024, 2048, 16);
  transpose_w<<<512, 256, 0, stream>>>(wv, wcatT, 1024, 3072, 16);
  transpose_w<<<1024, 256, 0, stream>>>(wo, woT, 2048, 0, 32);

  gemm_bf16<1><<<32 * 32, 256, 0, stream>>>(xo, wcatT, nullptr, qb, kb, vtb, 4096,
                                            4096, 2048, 32);
  rope_qk<<<6144, 256, 0, stream>>>(qb, kb, fc, fs);
  attn_fwd<<<dim3(32, 32), 256, 0, stream>>>(qb, kb, vtb, xo);
  gemm_bf16<0><<<32 * 16, 256, 0, stream>>>(xo, woT, out, nullptr, nullptr, nullptr,
                                            4096, 2048, 2048, 16);
}

// Round 2
// 302.338 us; speedup vs baseline: 1.6652x; 1.6652x over previous
//
#include <hip/hip_runtime.h>

typedef unsigned short u16;
typedef short bf16x8 __attribute__((ext_vector_type(8)));
typedef float f32x4 __attribute__((ext_vector_type(4)));
typedef unsigned int u32x4 __attribute__((ext_vector_type(4)));
typedef unsigned short u16x4 __attribute__((ext_vector_type(4)));
typedef unsigned short u16x8 __attribute__((ext_vector_type(8)));

#define S_LEN 2048
#define NHEAD 16
#define NKV 8
#define HD 128

__device__ __forceinline__ u16 f2bf(float f) {
  unsigned u = __builtin_bit_cast(unsigned, f);
  u = (u + 0x7FFFu + ((u >> 16) & 1u)) >> 16;
  return (u16)u;
}
__device__ __forceinline__ float bf2f(u16 h) {
  unsigned u = ((unsigned)h) << 16;
  return __builtin_bit_cast(float, u);
}

__device__ __forceinline__ void gl_lds16(const void* g, void* l) {
  __builtin_amdgcn_global_load_lds(
      (const __attribute__((address_space(1))) unsigned int*)g,
      (__attribute__((address_space(3))) unsigned int*)l, 16, 0, 0);
}

__device__ __forceinline__ float redmax16(float v) {
  v = fmaxf(v, __shfl_xor(v, 1));
  v = fmaxf(v, __shfl_xor(v, 2));
  v = fmaxf(v, __shfl_xor(v, 4));
  v = fmaxf(v, __shfl_xor(v, 8));
  return v;
}

// ---------------- elementwise f32 -> bf16 ----------------
__global__ __launch_bounds__(256) void conv_bf16(const float* __restrict__ in,
                                                 u16* __restrict__ out, int n4) {
  int i = blockIdx.x * 256 + threadIdx.x;
  if (i >= n4) return;
  f32x4 v = *(const f32x4*)(in + (size_t)i * 4);
  u16x4 o;
#pragma unroll
  for (int j = 0; j < 4; ++j) o[j] = f2bf(v[j]);
  *(u16x4*)(out + (size_t)i * 4) = o;
}

// ---------- transpose f32 [K][N] -> bf16 [roff+n][Kout=2048] ----------
__global__ __launch_bounds__(256) void transpose_w(const float* __restrict__ in,
                                                   u16* __restrict__ out, int N,
                                                   int roff, int nx) {
  __shared__ float tile[64][65];
  int bx = blockIdx.x % nx;  // n tile
  int by = blockIdx.x / nx;  // k tile
  int k0 = by * 64, n0 = bx * 64;
  int tx = threadIdx.x & 63, ty = threadIdx.x >> 6;
#pragma unroll
  for (int p = 0; p < 16; ++p) {
    int r = p * 4 + ty;
    tile[r][tx] = in[(size_t)(k0 + r) * N + n0 + tx];
  }
  __syncthreads();
#pragma unroll
  for (int p = 0; p < 16; ++p) {
    int r = p * 4 + ty;  // output row within tile -> n
    out[(size_t)(roff + n0 + r) * 2048 + k0 + tx] = f2bf(tile[tx][r]);
  }
}

// ---------------- RoPE in-place on Q (scaled) and K ----------------
// Q scale folds 1/sqrt(HD) AND log2(e) so attention exp is a bare v_exp_f32.
__global__ __launch_bounds__(256) void rope_qk(u16* __restrict__ q, u16* __restrict__ k,
                                               const float* __restrict__ fc,
                                               const float* __restrict__ fs) {
  const int QC = 2 * NHEAD * S_LEN * HD / 8;  // 1048576 chunks of 8 elems
  const int KC = 2 * NKV * S_LEN * HD / 8;    // 524288
  int i = blockIdx.x * 256 + threadIdx.x;
  if (i >= QC + KC) return;
  u16* base;
  float scale;
  size_t e;
  if (i < QC) {
    base = q;
    e = (size_t)i * 8;
    scale = 0.12751744540368598f;  // log2(e)/sqrt(128)
  } else {
    base = k;
    e = (size_t)(i - QC) * 8;
    scale = 1.0f;
  }
  int d8 = (int)(e & 127);
  int s = (int)((e >> 7) & (S_LEN - 1));
  int dp0 = d8 >> 1;
  u16x8 v = *(const u16x8*)(base + e);
  u16x8 o;
#pragma unroll
  for (int p = 0; p < 4; ++p) {
    float xr = bf2f(v[2 * p]), xi = bf2f(v[2 * p + 1]);
    float c = fc[s * 64 + dp0 + p], sn = fs[s * 64 + dp0 + p];
    o[2 * p] = f2bf((xr * c - xi * sn) * scale);
    o[2 * p + 1] = f2bf((xr * sn + xi * c) * scale);
  }
  *(u16x8*)(base + e) = o;
}

// ---------------- 128x128 bf16 GEMM, B given transposed [N][K] ----------------
// EPI 0: f32 C [M][N].  EPI 1: scatter bf16 to Q/K head-major + V transposed.
template <int EPI>
__global__ __launch_bounds__(256) void gemm_bf16(
    const u16* __restrict__ A, const u16* __restrict__ Bt, float* __restrict__ Cf,
    u16* __restrict__ Qo, u16* __restrict__ Ko, u16* __restrict__ Vo, int M, int N,
    int K, int ntn) {
  __shared__ __align__(16) u16 As[128 * 32];
  __shared__ __align__(16) u16 Bs[128 * 32];

  const int t = threadIdx.x;
  const int w = t >> 6, l = t & 63, lh = l >> 4, ll = l & 15;
  const int wm = w >> 1, wn = w & 1;
  const int tm = blockIdx.x / ntn, tn = blockIdx.x % ntn;

  const u16* Ab = A + (size_t)tm * 128 * K;
  const u16* Bb = Bt + (size_t)tn * 128 * K;

  const int srow = t >> 2;
  const int scol = (t & 3) * 8;

  f32x4 acc[4][4] = {};

  for (int kt = 0; kt < K; kt += 32) {
    gl_lds16(Ab + (size_t)srow * K + kt + scol, As + t * 8);
    gl_lds16(Ab + (size_t)(64 + srow) * K + kt + scol, As + 2048 + t * 8);
    gl_lds16(Bb + (size_t)srow * K + kt + scol, Bs + t * 8);
    gl_lds16(Bb + (size_t)(64 + srow) * K + kt + scol, Bs + 2048 + t * 8);
    __syncthreads();
    bf16x8 af[4], bfr[4];
#pragma unroll
    for (int m = 0; m < 4; ++m)
      af[m] = *(const bf16x8*)(As + (wm * 64 + m * 16 + ll) * 32 + lh * 8);
#pragma unroll
    for (int n = 0; n < 4; ++n)
      bfr[n] = *(const bf16x8*)(Bs + (wn * 64 + n * 16 + ll) * 32 + lh * 8);
#pragma unroll
    for (int m = 0; m < 4; ++m)
#pragma unroll
      for (int n = 0; n < 4; ++n)
        acc[m][n] = __builtin_amdgcn_mfma_f32_16x16x32_bf16(af[m], bfr[n], acc[m][n], 0, 0, 0);
    __syncthreads();
  }

#pragma unroll
  for (int m = 0; m < 4; ++m)
#pragma unroll
    for (int n = 0; n < 4; ++n)
#pragma unroll
      for (int j = 0; j < 4; ++j) {
        int row = tm * 128 + wm * 64 + m * 16 + lh * 4 + j;
        int col = tn * 128 + wn * 64 + n * 16 + ll;
        if constexpr (EPI == 0) {
          Cf[(size_t)row * N + col] = acc[m][n][j];
        } else {
          int b = row >> 11, s = row & (S_LEN - 1);
          u16 val = f2bf(acc[m][n][j]);
          if (col < 2048) {
            int hh = col >> 7, d = col & 127;
            Qo[(((size_t)b * NHEAD + hh) * S_LEN + s) * HD + d] = val;
          } else if (col < 3072) {
            int kh = (col - 2048) >> 7, d = col & 127;
            Ko[(((size_t)b * NKV + kh) * S_LEN + s) * HD + d] = val;
          } else {
            int kh = (col - 3072) >> 7, d = col & 127;
            Vo[(((size_t)b * NKV + kh) * HD + d) * S_LEN + s] = val;
          }
        }
      }
}

// ---------------- causal GQA flash attention (balanced pairing) ----------------
// Q [B*H][S][HD] (pre-scaled by log2e/sqrt(HD)), K [B*KV][S][HD], Vt [B*KV][HD][S]
// -> O bf16 [B*S][2048]
// Block p: bh = p>>4, handles q-tiles {pair, 31-pair} sequentially -> cost 33 for all.
__global__ __launch_bounds__(256) void attn_fwd(const u16* __restrict__ Q,
                                                const u16* __restrict__ Kh,
                                                const u16* __restrict__ Vt,
                                                u16* __restrict__ O) {
  __shared__ __align__(16) u16 Ks[64 * 136];
  __shared__ __align__(16) u16 Vs[128 * 72];
  __shared__ __align__(16) u16 Ps[4 * 16 * 64];

  const int t = threadIdx.x;
  const int w = t >> 6, l = t & 63, lh = l >> 4, ll = l & 15;
  const int bh = blockIdx.x >> 4;
  const int pair = blockIdx.x & 15;
  const int b = bh >> 4, h = bh & 15;
  const int bkv = b * NKV + (h >> 1);

  const u16* Qb = Q + (size_t)bh * S_LEN * HD;
  const u16* Kb = Kh + (size_t)bkv * S_LEN * HD;
  const u16* Vb = Vt + (size_t)bkv * HD * S_LEN;

  const int krow = t >> 4, kcol = (t & 15) * 8;
  const int vrow = t >> 3, vcol = (t & 7) * 8;

  const bf16x8 vones = {0x3F80, 0x3F80, 0x3F80, 0x3F80, 0x3F80, 0x3F80, 0x3F80, 0x3F80};

  auto loadKV = [&](int tile, u32x4 (&kr)[4], u32x4 (&vr)[4]) {
    const int kv0 = tile * 64;
#pragma unroll
    for (int p = 0; p < 4; ++p)
      kr[p] = *(const u32x4*)(Kb + (size_t)(kv0 + p * 16 + krow) * HD + kcol);
#pragma unroll
    for (int p = 0; p < 4; ++p)
      vr[p] = *(const u32x4*)(Vb + (size_t)(p * 32 + vrow) * S_LEN + kv0 + vcol);
  };
  auto storeKV = [&](u32x4 (&kr)[4], u32x4 (&vr)[4]) {
#pragma unroll
    for (int p = 0; p < 4; ++p)
      *(u32x4*)(Ks + (p * 16 + krow) * 136 + kcol) = kr[p];
#pragma unroll
    for (int p = 0; p < 4; ++p)
      *(u32x4*)(Vs + (p * 32 + vrow) * 72 + vcol) = vr[p];
  };

  for (int hf = 0; hf < 2; ++hf) {
    const int qt = hf ? (31 - pair) : pair;
    const int q0 = qt * 64;

    bf16x8 qf[4];
    const int qrow = q0 + w * 16 + ll;
#pragma unroll
    for (int c = 0; c < 4; ++c)
      qf[c] = *(const bf16x8*)(Qb + (size_t)qrow * HD + c * 32 + lh * 8);

    f32x4 accO[8] = {};
    f32x4 accL = {0.f, 0.f, 0.f, 0.f};
    float mrow[4] = {-1e30f, -1e30f, -1e30f, -1e30f};

    u32x4 kr[4], vr[4];
    loadKV(0, kr, vr);
    storeKV(kr, vr);
    __syncthreads();

    const int nt = qt + 1;
    for (int tt = 0; tt < nt; ++tt) {
      if (tt + 1 < nt) loadKV(tt + 1, kr, vr);  // async: overlaps compute below

      // S = Q K^T  (16 q rows x 64 kv), already in log2 domain
      f32x4 sf[4];
#pragma unroll
      for (int f = 0; f < 4; ++f) {
        sf[f] = f32x4{0.f, 0.f, 0.f, 0.f};
#pragma unroll
        for (int c = 0; c < 4; ++c) {
          bf16x8 kf = *(const bf16x8*)(Ks + (f * 16 + ll) * 136 + c * 32 + lh * 8);
          sf[f] = __builtin_amdgcn_mfma_f32_16x16x32_bf16(qf[c], kf, sf[f], 0, 0, 0);
        }
      }

      if (tt == nt - 1) {  // diagonal tile: causal mask
        const int kv0 = tt * 64;
#pragma unroll
        for (int f = 0; f < 4; ++f)
#pragma unroll
          for (int j = 0; j < 4; ++j) {
            int kvg = kv0 + f * 16 + ll;
            int qg = q0 + w * 16 + lh * 4 + j;
            if (kvg > qg) sf[f][j] = -1e30f;
          }
      }

      float corr[4];
#pragma unroll
      for (int j = 0; j < 4; ++j) {
        float mx = fmaxf(fmaxf(sf[0][j], sf[1][j]), fmaxf(sf[2][j], sf[3][j]));
        mx = redmax16(mx);
        float mnew = fmaxf(mrow[j], mx);
        corr[j] = __builtin_amdgcn_exp2f(mrow[j] - mnew);
        mrow[j] = mnew;
#pragma unroll
        for (int f = 0; f < 4; ++f) sf[f][j] = __builtin_amdgcn_exp2f(sf[f][j] - mnew);
      }
#pragma unroll
      for (int n = 0; n < 8; ++n)
#pragma unroll
        for (int j = 0; j < 4; ++j) accO[n][j] *= corr[j];
#pragma unroll
      for (int j = 0; j < 4; ++j) accL[j] *= corr[j];

      // P -> LDS (per-wave tile, XOR-swizzled rows, stride 64 u16)
      char* Pw = (char*)(Ps + w * 16 * 64);
#pragma unroll
      for (int f = 0; f < 4; ++f)
#pragma unroll
        for (int j = 0; j < 4; ++j) {
          int rr = lh * 4 + j, cc = f * 16 + ll;
          unsigned bo = (unsigned)(rr * 128 + cc * 2) ^ (unsigned)((rr & 7) << 4);
          *(u16*)(Pw + bo) = f2bf(sf[f][j]);
        }

      // O += P V ; row-sum via ones column
#pragma unroll
      for (int kc = 0; kc < 2; ++kc) {
        unsigned bo =
            (unsigned)(ll * 128 + (kc * 32 + lh * 8) * 2) ^ (unsigned)((ll & 7) << 4);
        bf16x8 pf = *(const bf16x8*)(Pw + bo);
#pragma unroll
        for (int n = 0; n < 8; ++n) {
          bf16x8 vf = *(const bf16x8*)(Vs + (n * 16 + ll) * 72 + kc * 32 + lh * 8);
          accO[n] = __builtin_amdgcn_mfma_f32_16x16x32_bf16(pf, vf, accO[n], 0, 0, 0);
        }
        accL = __builtin_amdgcn_mfma_f32_16x16x32_bf16(pf, vones, accL, 0, 0, 0);
      }

      __syncthreads();  // all waves done reading Ks/Vs
      if (tt + 1 < nt) storeKV(kr, vr);
      __syncthreads();
    }

    float inv[4];
#pragma unroll
    for (int j = 0; j < 4; ++j) inv[j] = 1.0f / accL[j];
    const size_t orow = (size_t)(b * S_LEN + q0 + w * 16 + lh * 4) * 2048 + h * HD;
#pragma unroll
    for (int n = 0; n < 8; ++n)
#pragma unroll
      for (int j = 0; j < 4; ++j)
        O[orow + (size_t)j * 2048 + n * 16 + ll] = f2bf(accO[n][j] * inv[j]);
  }
}

extern "C" void kernel_launch(void* const* d_in, const int* in_sizes, int n_in,
                              void* d_out, int out_size, void* d_ws, size_t ws_size,
                              hipStream_t stream) {
  (void)in_sizes;
  (void)n_in;
  (void)out_size;
  (void)ws_size;
  const float* x = (const float*)d_in[0];
  const float* fc = (const float*)d_in[1];
  const float* fs = (const float*)d_in[2];
  const float* wq = (const float*)d_in[3];
  const float* wk = (const float*)d_in[4];
  const float* wv = (const float*)d_in[5];
  const float* wo = (const float*)d_in[6];
  float* out = (float*)d_out;

  char* ws = (char*)d_ws;
  u16* wcatT = (u16*)ws;                          // [4096][2048] bf16  16.78 MB
  u16* woT = (u16*)(ws + 16777216);               // [2048][2048]        8.39 MB
  u16* xo = (u16*)(ws + 25165824);                // x_bf16 then O      16.78 MB
  u16* qb = (u16*)(ws + 41943040);                // [32][2048][128]    16.78 MB
  u16* kb = (u16*)(ws + 58720256);                // [16][2048][128]     8.39 MB
  u16* vtb = (u16*)(ws + 67108864);               // [16][128][2048]     8.39 MB
  // total 75,497,472 bytes

  conv_bf16<<<8192, 256, 0, stream>>>(x, xo, 2097152);
  transpose_w<<<1024, 256, 0, stream>>>(wq, wcatT, 2048, 0, 32);
  transpose_w<<<512, 256, 0, stream>>>(wk, wcatT, 1024, 2048, 16);
  transpose_w<<<512, 256, 0, stream>>>(wv, wcatT, 1024, 3072, 16);
  transpose_w<<<1024, 256, 0, stream>>>(wo, woT, 2048, 0, 32);

  gemm_bf16<1><<<32 * 32, 256, 0, stream>>>(xo, wcatT, nullptr, qb, kb, vtb, 4096,
                                            4096, 2048, 32);
  rope_qk<<<6144, 256, 0, stream>>>(qb, kb, fc, fs);
  attn_fwd<<<512, 256, 0, stream>>>(qb, kb, vtb, xo);
  gemm_bf16<0><<<32 * 16, 256, 0, stream>>>(xo, woT, out, nullptr, nullptr, nullptr,
                                            4096, 2048, 2048, 16);
}

// Round 3
// 266.681 us; speedup vs baseline: 1.8879x; 1.1337x over previous
//
#include <hip/hip_runtime.h>

typedef unsigned short u16;
typedef short bf16x8 __attribute__((ext_vector_type(8)));
typedef float f32x4 __attribute__((ext_vector_type(4)));
typedef unsigned int u32x4 __attribute__((ext_vector_type(4)));
typedef unsigned short u16x4 __attribute__((ext_vector_type(4)));
typedef unsigned short u16x8 __attribute__((ext_vector_type(8)));

#define S_LEN 2048
#define NHEAD 16
#define NKV 8
#define HD 128

__device__ __forceinline__ u16 f2bf(float f) {
  unsigned u = __builtin_bit_cast(unsigned, f);
  u = (u + 0x7FFFu + ((u >> 16) & 1u)) >> 16;
  return (u16)u;
}
__device__ __forceinline__ float bf2f(u16 h) {
  unsigned u = ((unsigned)h) << 16;
  return __builtin_bit_cast(float, u);
}

__device__ __forceinline__ void gl_lds16(const void* g, void* l) {
  __builtin_amdgcn_global_load_lds(
      (const __attribute__((address_space(1))) unsigned int*)g,
      (__attribute__((address_space(3))) unsigned int*)l, 16, 0, 0);
}

__device__ __forceinline__ float redmax16(float v) {
  v = fmaxf(v, __shfl_xor(v, 1));
  v = fmaxf(v, __shfl_xor(v, 2));
  v = fmaxf(v, __shfl_xor(v, 4));
  v = fmaxf(v, __shfl_xor(v, 8));
  return v;
}

// ---------------- elementwise f32 -> bf16 ----------------
__global__ __launch_bounds__(256) void conv_bf16(const float* __restrict__ in,
                                                 u16* __restrict__ out, int n4) {
  int i = blockIdx.x * 256 + threadIdx.x;
  if (i >= n4) return;
  f32x4 v = *(const f32x4*)(in + (size_t)i * 4);
  u16x4 o;
#pragma unroll
  for (int j = 0; j < 4; ++j) o[j] = f2bf(v[j]);
  *(u16x4*)(out + (size_t)i * 4) = o;
}

// ---- fused transpose of wq/wk/wv/wo: f32 [K][N] -> bf16 [roff+n][2048] ----
__global__ __launch_bounds__(256) void transpose_w4(
    const float* __restrict__ wq, const float* __restrict__ wk,
    const float* __restrict__ wv, const float* __restrict__ wo,
    u16* __restrict__ wcatT, u16* __restrict__ woT) {
  __shared__ float tile[64][65];
  int id = blockIdx.x;
  const float* in;
  u16* out;
  int N, roff, nx;
  if (id < 1024) {
    in = wq; out = wcatT; N = 2048; roff = 0; nx = 32;
  } else if (id < 1536) {
    in = wk; out = wcatT; N = 1024; roff = 2048; nx = 16; id -= 1024;
  } else if (id < 2048) {
    in = wv; out = wcatT; N = 1024; roff = 3072; nx = 16; id -= 1536;
  } else {
    in = wo; out = woT; N = 2048; roff = 0; nx = 32; id -= 2048;
  }
  int bx = id % nx;  // n tile
  int by = id / nx;  // k tile
  int k0 = by * 64, n0 = bx * 64;
  int tx = threadIdx.x & 63, ty = threadIdx.x >> 6;
#pragma unroll
  for (int p = 0; p < 16; ++p) {
    int r = p * 4 + ty;
    tile[r][tx] = in[(size_t)(k0 + r) * N + n0 + tx];
  }
  __syncthreads();
#pragma unroll
  for (int p = 0; p < 16; ++p) {
    int r = p * 4 + ty;
    out[(size_t)(roff + n0 + r) * 2048 + k0 + tx] = f2bf(tile[tx][r]);
  }
}

// ---------------- RoPE in-place on Q (scaled) and K ----------------
// Q scale folds 1/sqrt(HD) AND log2(e) so attention exp is a bare v_exp_f32.
__global__ __launch_bounds__(256) void rope_qk(u16* __restrict__ q, u16* __restrict__ k,
                                               const float* __restrict__ fc,
                                               const float* __restrict__ fs) {
  const int QC = 2 * NHEAD * S_LEN * HD / 8;
  const int KC = 2 * NKV * S_LEN * HD / 8;
  int i = blockIdx.x * 256 + threadIdx.x;
  if (i >= QC + KC) return;
  u16* base;
  float scale;
  size_t e;
  if (i < QC) {
    base = q;
    e = (size_t)i * 8;
    scale = 0.12751744540368598f;  // log2(e)/sqrt(128)
  } else {
    base = k;
    e = (size_t)(i - QC) * 8;
    scale = 1.0f;
  }
  int d8 = (int)(e & 127);
  int s = (int)((e >> 7) & (S_LEN - 1));
  int dp0 = d8 >> 1;
  u16x8 v = *(const u16x8*)(base + e);
  u16x8 o;
#pragma unroll
  for (int p = 0; p < 4; ++p) {
    float xr = bf2f(v[2 * p]), xi = bf2f(v[2 * p + 1]);
    float c = fc[s * 64 + dp0 + p], sn = fs[s * 64 + dp0 + p];
    o[2 * p] = f2bf((xr * c - xi * sn) * scale);
    o[2 * p + 1] = f2bf((xr * sn + xi * c) * scale);
  }
  *(u16x8*)(base + e) = o;
}

// -------- 128xBN bf16 GEMM, BK=64, swizzled LDS, B given transposed [N][K] -----
// EPI 0: f32 C [M][N].  EPI 1: scatter bf16 to Q/K/V head-major [b][h][s][d].
template <int EPI, int BN>
__global__ __launch_bounds__(256) void gemm_bf16(
    const u16* __restrict__ A, const u16* __restrict__ Bt, float* __restrict__ Cf,
    u16* __restrict__ Qo, u16* __restrict__ Ko, u16* __restrict__ Vo, int M, int N,
    int K, int ntn) {
  __shared__ __align__(16) u16 As[128 * 64];
  __shared__ __align__(16) u16 Bs[BN * 64];

  const int t = threadIdx.x;
  const int w = t >> 6, l = t & 63, lh = l >> 4, ll = l & 15;
  const int wm = w >> 1, wn = w & 1;

  // bijective XCD swizzle (grid % 8 == 0)
  const int nwg = gridDim.x;
  const int bid = blockIdx.x;
  const int swzb = (bid & 7) * (nwg >> 3) + (bid >> 3);
  const int tm = swzb / ntn, tn = swzb % ntn;

  const u16* Ab = A + (size_t)tm * 128 * K;
  const u16* Bb = Bt + (size_t)tn * BN * K;

  // staging: chunk covers 32 rows; swizzled source slot (inverse of read swizzle)
  const int tr = t >> 3;                  // row within chunk
  const int tc = (t & 7) ^ (tr & 7);      // 16B slot within 128B row
  const int sw = (ll & 7) << 3;           // read-side swizzle (u16 units)

  constexpr int NF = BN / 32;             // per-wave n-frags
  f32x4 acc[4][NF] = {};

  for (int kt = 0; kt < K; kt += 64) {
#pragma unroll
    for (int c = 0; c < 4; ++c)
      gl_lds16(Ab + (size_t)(c * 32 + tr) * K + kt + tc * 8, As + c * 2048 + t * 8);
#pragma unroll
    for (int c = 0; c < BN / 32; ++c)
      gl_lds16(Bb + (size_t)(c * 32 + tr) * K + kt + tc * 8, Bs + c * 2048 + t * 8);
    __syncthreads();
#pragma unroll
    for (int kk = 0; kk < 2; ++kk) {
      const int cb = (kk * 32 + lh * 8) ^ sw;
      bf16x8 af[4], bfr[NF];
#pragma unroll
      for (int m = 0; m < 4; ++m)
        af[m] = *(const bf16x8*)(As + (wm * 64 + m * 16 + ll) * 64 + cb);
#pragma unroll
      for (int n = 0; n < NF; ++n)
        bfr[n] = *(const bf16x8*)(Bs + (wn * (BN / 2) + n * 16 + ll) * 64 + cb);
#pragma unroll
      for (int m = 0; m < 4; ++m)
#pragma unroll
        for (int n = 0; n < NF; ++n)
          acc[m][n] =
              __builtin_amdgcn_mfma_f32_16x16x32_bf16(af[m], bfr[n], acc[m][n], 0, 0, 0);
    }
    __syncthreads();
  }

#pragma unroll
  for (int m = 0; m < 4; ++m)
#pragma unroll
    for (int n = 0; n < NF; ++n)
#pragma unroll
      for (int j = 0; j < 4; ++j) {
        int row = tm * 128 + wm * 64 + m * 16 + lh * 4 + j;
        int col = tn * BN + wn * (BN / 2) + n * 16 + ll;
        if constexpr (EPI == 0) {
          Cf[(size_t)row * N + col] = acc[m][n][j];
        } else {
          int b = row >> 11, s = row & (S_LEN - 1);
          u16 val = f2bf(acc[m][n][j]);
          int d = col & 127;
          if (col < 2048) {
            int hh = col >> 7;
            Qo[(((size_t)b * NHEAD + hh) * S_LEN + s) * HD + d] = val;
          } else if (col < 3072) {
            int kh = (col >> 7) & 7;
            Ko[(((size_t)b * NKV + kh) * S_LEN + s) * HD + d] = val;
          } else {
            int kh = (col >> 7) & 7;
            Vo[(((size_t)b * NKV + kh) * S_LEN + s) * HD + d] = val;
          }
        }
      }
}

// ---- V [bkv][2048][128] -> Vt [bkv][128][2048] (LDS tiled transpose) ----
__global__ __launch_bounds__(256) void transpose_v(const u16* __restrict__ V,
                                                   u16* __restrict__ Vt) {
  __shared__ u16 tile[64][72];
  int id = blockIdx.x;
  int bkv = id >> 6;
  int dt = (id >> 5) & 1;
  int st = id & 31;
  const u16* Vb = V + (size_t)bkv * S_LEN * HD;
  u16* Vo = Vt + (size_t)bkv * HD * S_LEN;
  int r = threadIdx.x >> 3, c8 = (threadIdx.x & 7) * 8;
#pragma unroll
  for (int it = 0; it < 2; ++it) {
    int rr = it * 32 + r;
    *(u16x8*)(&tile[rr][c8]) =
        *(const u16x8*)(Vb + (size_t)(st * 64 + rr) * HD + dt * 64 + c8);
  }
  __syncthreads();
#pragma unroll
  for (int it = 0; it < 2; ++it) {
    int rr = it * 32 + r;  // d index
    u16x8 o;
#pragma unroll
    for (int j = 0; j < 8; ++j) o[j] = tile[c8 + j][rr];
    *(u16x8*)(Vo + (size_t)(dt * 64 + rr) * S_LEN + st * 64 + c8) = o;
  }
}

// ---------------- causal GQA flash attention (balanced pairing) ----------------
__global__ __launch_bounds__(256) void attn_fwd(const u16* __restrict__ Q,
                                                const u16* __restrict__ Kh,
                                                const u16* __restrict__ Vt,
                                                u16* __restrict__ O) {
  __shared__ __align__(16) u16 Ks[64 * 136];
  __shared__ __align__(16) u16 Vs[128 * 72];
  __shared__ __align__(16) u16 Ps[4 * 16 * 64];

  const int t = threadIdx.x;
  const int w = t >> 6, l = t & 63, lh = l >> 4, ll = l & 15;
  const int bid = blockIdx.x;
  const int swzb = (bid & 7) * 64 + (bid >> 3);  // 512 blocks
  const int bh = swzb >> 4;
  const int pair = swzb & 15;
  const int b = bh >> 4, h = bh & 15;
  const int bkv = b * NKV + (h >> 1);

  const u16* Qb = Q + (size_t)bh * S_LEN * HD;
  const u16* Kb = Kh + (size_t)bkv * S_LEN * HD;
  const u16* Vb = Vt + (size_t)bkv * HD * S_LEN;

  const int krow = t >> 4, kcol = (t & 15) * 8;
  const int vrow = t >> 3, vcol = (t & 7) * 8;

  const bf16x8 vones = {0x3F80, 0x3F80, 0x3F80, 0x3F80, 0x3F80, 0x3F80, 0x3F80, 0x3F80};

  auto loadKV = [&](int tile, u32x4 (&kr)[4], u32x4 (&vr)[4]) {
    const int kv0 = tile * 64;
#pragma unroll
    for (int p = 0; p < 4; ++p)
      kr[p] = *(const u32x4*)(Kb + (size_t)(kv0 + p * 16 + krow) * HD + kcol);
#pragma unroll
    for (int p = 0; p < 4; ++p)
      vr[p] = *(const u32x4*)(Vb + (size_t)(p * 32 + vrow) * S_LEN + kv0 + vcol);
  };
  auto storeKV = [&](u32x4 (&kr)[4], u32x4 (&vr)[4]) {
#pragma unroll
    for (int p = 0; p < 4; ++p)
      *(u32x4*)(Ks + (p * 16 + krow) * 136 + kcol) = kr[p];
#pragma unroll
    for (int p = 0; p < 4; ++p)
      *(u32x4*)(Vs + (p * 32 + vrow) * 72 + vcol) = vr[p];
  };

  for (int hf = 0; hf < 2; ++hf) {
    const int qt = hf ? (31 - pair) : pair;
    const int q0 = qt * 64;

    bf16x8 qf[4];
    const int qrow = q0 + w * 16 + ll;
#pragma unroll
    for (int c = 0; c < 4; ++c)
      qf[c] = *(const bf16x8*)(Qb + (size_t)qrow * HD + c * 32 + lh * 8);

    f32x4 accO[8] = {};
    f32x4 accL = {0.f, 0.f, 0.f, 0.f};
    float mrow[4] = {-1e30f, -1e30f, -1e30f, -1e30f};

    u32x4 kr[4], vr[4];
    loadKV(0, kr, vr);
    storeKV(kr, vr);
    __syncthreads();

    const int nt = qt + 1;
    for (int tt = 0; tt < nt; ++tt) {
      if (tt + 1 < nt) loadKV(tt + 1, kr, vr);  // overlaps compute below

      f32x4 sf[4];
#pragma unroll
      for (int f = 0; f < 4; ++f) {
        sf[f] = f32x4{0.f, 0.f, 0.f, 0.f};
#pragma unroll
        for (int c = 0; c < 4; ++c) {
          bf16x8 kf = *(const bf16x8*)(Ks + (f * 16 + ll) * 136 + c * 32 + lh * 8);
          sf[f] = __builtin_amdgcn_mfma_f32_16x16x32_bf16(qf[c], kf, sf[f], 0, 0, 0);
        }
      }

      if (tt == nt - 1) {  // diagonal tile: causal mask
        const int kv0 = tt * 64;
#pragma unroll
        for (int f = 0; f < 4; ++f)
#pragma unroll
          for (int j = 0; j < 4; ++j) {
            int kvg = kv0 + f * 16 + ll;
            int qg = q0 + w * 16 + lh * 4 + j;
            if (kvg > qg) sf[f][j] = -1e30f;
          }
      }

      float corr[4];
#pragma unroll
      for (int j = 0; j < 4; ++j) {
        float mx = fmaxf(fmaxf(sf[0][j], sf[1][j]), fmaxf(sf[2][j], sf[3][j]));
        mx = redmax16(mx);
        float mnew = fmaxf(mrow[j], mx);
        corr[j] = __builtin_amdgcn_exp2f(mrow[j] - mnew);
        mrow[j] = mnew;
#pragma unroll
        for (int f = 0; f < 4; ++f) sf[f][j] = __builtin_amdgcn_exp2f(sf[f][j] - mnew);
      }
#pragma unroll
      for (int n = 0; n < 8; ++n)
#pragma unroll
        for (int j = 0; j < 4; ++j) accO[n][j] *= corr[j];
#pragma unroll
      for (int j = 0; j < 4; ++j) accL[j] *= corr[j];

      char* Pw = (char*)(Ps + w * 16 * 64);
#pragma unroll
      for (int f = 0; f < 4; ++f)
#pragma unroll
        for (int j = 0; j < 4; ++j) {
          int rr = lh * 4 + j, cc = f * 16 + ll;
          unsigned bo = (unsigned)(rr * 128 + cc * 2) ^ (unsigned)((rr & 7) << 4);
          *(u16*)(Pw + bo) = f2bf(sf[f][j]);
        }

#pragma unroll
      for (int kc = 0; kc < 2; ++kc) {
        unsigned bo =
            (unsigned)(ll * 128 + (kc * 32 + lh * 8) * 2) ^ (unsigned)((ll & 7) << 4);
        bf16x8 pf = *(const bf16x8*)(Pw + bo);
#pragma unroll
        for (int n = 0; n < 8; ++n) {
          bf16x8 vf = *(const bf16x8*)(Vs + (n * 16 + ll) * 72 + kc * 32 + lh * 8);
          accO[n] = __builtin_amdgcn_mfma_f32_16x16x32_bf16(pf, vf, accO[n], 0, 0, 0);
        }
        accL = __builtin_amdgcn_mfma_f32_16x16x32_bf16(pf, vones, accL, 0, 0, 0);
      }

      __syncthreads();
      if (tt + 1 < nt) storeKV(kr, vr);
      __syncthreads();
    }

    float inv[4];
#pragma unroll
    for (int j = 0; j < 4; ++j) inv[j] = 1.0f / accL[j];
    const size_t orow = (size_t)(b * S_LEN + q0 + w * 16 + lh * 4) * 2048 + h * HD;
#pragma unroll
    for (int n = 0; n < 8; ++n)
#pragma unroll
      for (int j = 0; j < 4; ++j)
        O[orow + (size_t)j * 2048 + n * 16 + ll] = f2bf(accO[n][j] * inv[j]);
  }
}

extern "C" void kernel_launch(void* const* d_in, const int* in_sizes, int n_in,
                              void* d_out, int out_size, void* d_ws, size_t ws_size,
                              hipStream_t stream) {
  (void)in_sizes;
  (void)n_in;
  (void)out_size;
  (void)ws_size;
  const float* x = (const float*)d_in[0];
  const float* fc = (const float*)d_in[1];
  const float* fs = (const float*)d_in[2];
  const float* wq = (const float*)d_in[3];
  const float* wk = (const float*)d_in[4];
  const float* wv = (const float*)d_in[5];
  const float* wo = (const float*)d_in[6];
  float* out = (float*)d_out;

  char* ws = (char*)d_ws;
  u16* wcatT = (u16*)ws;             // [4096][2048] bf16  16.78 MB (dead after gemm<1>)
  u16* vtb = (u16*)ws;               // aliases wcatT: [16][128][2048]  8.39 MB
  u16* woT = (u16*)(ws + 16777216);  // [2048][2048]        8.39 MB
  u16* xo = (u16*)(ws + 25165824);   // x_bf16 then O      16.78 MB
  u16* qb = (u16*)(ws + 41943040);   // [32][2048][128]    16.78 MB
  u16* kb = (u16*)(ws + 58720256);   // [16][2048][128]     8.39 MB
  u16* vb = (u16*)(ws + 67108864);   // [16][2048][128]     8.39 MB
  // total 75,497,472 bytes

  conv_bf16<<<8192, 256, 0, stream>>>(x, xo, 2097152);
  transpose_w4<<<3072, 256, 0, stream>>>(wq, wk, wv, wo, wcatT, woT);

  gemm_bf16<1, 128><<<32 * 32, 256, 0, stream>>>(xo, wcatT, nullptr, qb, kb, vb, 4096,
                                                 4096, 2048, 32);
  transpose_v<<<1024, 256, 0, stream>>>(vb, vtb);
  rope_qk<<<6144, 256, 0, stream>>>(qb, kb, fc, fs);
  attn_fwd<<<512, 256, 0, stream>>>(qb, kb, vtb, xo);
  gemm_bf16<0, 64><<<32 * 32, 256, 0, stream>>>(xo, woT, out, nullptr, nullptr, nullptr,
                                                4096, 2048, 2048, 32);
}

// Round 4
// 234.389 us; speedup vs baseline: 2.1480x; 1.1378x over previous
//
#include <hip/hip_runtime.h>

typedef unsigned short u16;
typedef short bf16x8 __attribute__((ext_vector_type(8)));
typedef float f32x4 __attribute__((ext_vector_type(4)));
typedef unsigned int u32x4 __attribute__((ext_vector_type(4)));
typedef unsigned short u16x4 __attribute__((ext_vector_type(4)));
typedef unsigned short u16x8 __attribute__((ext_vector_type(8)));

#define S_LEN 2048
#define NHEAD 16
#define NKV 8
#define HD 128

__device__ __forceinline__ u16 f2bf(float f) {
  unsigned u = __builtin_bit_cast(unsigned, f);
  u = (u + 0x7FFFu + ((u >> 16) & 1u)) >> 16;
  return (u16)u;
}
__device__ __forceinline__ float bf2f(u16 h) {
  unsigned u = ((unsigned)h) << 16;
  return __builtin_bit_cast(float, u);
}

__device__ __forceinline__ void gl_lds16(const void* g, void* l) {
  __builtin_amdgcn_global_load_lds(
      (const __attribute__((address_space(1))) unsigned int*)g,
      (__attribute__((address_space(3))) unsigned int*)l, 16, 0, 0);
}

__device__ __forceinline__ float redmax16(float v) {
  v = fmaxf(v, __shfl_xor(v, 1));
  v = fmaxf(v, __shfl_xor(v, 2));
  v = fmaxf(v, __shfl_xor(v, 4));
  v = fmaxf(v, __shfl_xor(v, 8));
  return v;
}

// ---------------- elementwise f32 -> bf16 ----------------
__global__ __launch_bounds__(256) void conv_bf16(const float* __restrict__ in,
                                                 u16* __restrict__ out, int n4) {
  int i = blockIdx.x * 256 + threadIdx.x;
  if (i >= n4) return;
  f32x4 v = *(const f32x4*)(in + (size_t)i * 4);
  u16x4 o;
#pragma unroll
  for (int j = 0; j < 4; ++j) o[j] = f2bf(v[j]);
  *(u16x4*)(out + (size_t)i * 4) = o;
}

// ---- fused transpose of wq/wk/wv/wo: f32 [K][N] -> bf16 [roff+n][2048] ----
__global__ __launch_bounds__(256) void transpose_w4(
    const float* __restrict__ wq, const float* __restrict__ wk,
    const float* __restrict__ wv, const float* __restrict__ wo,
    u16* __restrict__ wcatT, u16* __restrict__ woT) {
  __shared__ float tile[64][65];
  int id = blockIdx.x;
  const float* in;
  u16* out;
  int N, roff, nx;
  if (id < 1024) {
    in = wq; out = wcatT; N = 2048; roff = 0; nx = 32;
  } else if (id < 1536) {
    in = wk; out = wcatT; N = 1024; roff = 2048; nx = 16; id -= 1024;
  } else if (id < 2048) {
    in = wv; out = wcatT; N = 1024; roff = 3072; nx = 16; id -= 1536;
  } else {
    in = wo; out = woT; N = 2048; roff = 0; nx = 32; id -= 2048;
  }
  int bx = id % nx;
  int by = id / nx;
  int k0 = by * 64, n0 = bx * 64;
  int tx = threadIdx.x & 63, ty = threadIdx.x >> 6;
#pragma unroll
  for (int p = 0; p < 16; ++p) {
    int r = p * 4 + ty;
    tile[r][tx] = in[(size_t)(k0 + r) * N + n0 + tx];
  }
  __syncthreads();
#pragma unroll
  for (int p = 0; p < 16; ++p) {
    int r = p * 4 + ty;
    out[(size_t)(roff + n0 + r) * 2048 + k0 + tx] = f2bf(tile[tx][r]);
  }
}

// ---------------- RoPE in-place on Q (scaled) and K ----------------
__global__ __launch_bounds__(256) void rope_qk(u16* __restrict__ q, u16* __restrict__ k,
                                               const float* __restrict__ fc,
                                               const float* __restrict__ fs) {
  const int QC = 2 * NHEAD * S_LEN * HD / 8;
  const int KC = 2 * NKV * S_LEN * HD / 8;
  int i = blockIdx.x * 256 + threadIdx.x;
  if (i >= QC + KC) return;
  u16* base;
  float scale;
  size_t e;
  if (i < QC) {
    base = q;
    e = (size_t)i * 8;
    scale = 0.12751744540368598f;  // log2(e)/sqrt(128)
  } else {
    base = k;
    e = (size_t)(i - QC) * 8;
    scale = 1.0f;
  }
  int d8 = (int)(e & 127);
  int s = (int)((e >> 7) & (S_LEN - 1));
  int dp0 = d8 >> 1;
  u16x8 v = *(const u16x8*)(base + e);
  u16x8 o;
#pragma unroll
  for (int p = 0; p < 4; ++p) {
    float xr = bf2f(v[2 * p]), xi = bf2f(v[2 * p + 1]);
    float c = fc[s * 64 + dp0 + p], sn = fs[s * 64 + dp0 + p];
    o[2 * p] = f2bf((xr * c - xi * sn) * scale);
    o[2 * p + 1] = f2bf((xr * sn + xi * c) * scale);
  }
  *(u16x8*)(base + e) = o;
}

// ======== deep-pipelined GEMM: BMx256 tile, BK=32, 4 LDS buffers, ========
// ======== counted vmcnt (never 0 in steady state), 512 thr / 8 waves ======
// EPI 0: f32 C [M][N].  EPI 1: scatter bf16 to Q/K/V head-major [b][h][s][d].
template <int EPI, int BM>
__global__ __launch_bounds__(512, 2) void gemm8(
    const u16* __restrict__ A, const u16* __restrict__ Bt, float* __restrict__ Cf,
    u16* __restrict__ Qo, u16* __restrict__ Ko, u16* __restrict__ Vo, int N, int ntn) {
  constexpr int K = 2048, NT = K / 32;
  constexpr int ASZ = BM * 32, TSZ = ASZ + 256 * 32;
  constexpr int L = (BM + 256) / 128;  // gl_lds instrs per tile (4 or 3)
  __shared__ __align__(16) u16 lds[4][TSZ];

  const int t = threadIdx.x;
  const int l = t & 63, lh = l >> 4, ll = l & 15;
  const int w = t >> 6, wm = w >> 2, wn = w & 3;

  const int bid = blockIdx.x;
  const int swz = (bid & 7) * (gridDim.x >> 3) + (bid >> 3);  // XCD chunk swizzle
  const int tm = swz / ntn, tn = swz % ntn;

  const u16* Ab = A + (size_t)tm * BM * K;
  const u16* Bb = Bt + (size_t)tn * 256 * K;

  const int sr = t >> 2;                       // staging row 0..127
  const int sc8 = ((t & 3) ^ (sr & 3)) * 8;    // pre-swizzled source col (u16)
  const int cb = (lh ^ (ll & 3)) * 8;          // read-side swizzled col (u16)

  f32x4 acc[BM / 32][4] = {};

  auto STAGE = [&](int tau) {
    const int kt = tau * 32;
    u16* buf = &lds[tau & 3][0];
#pragma unroll
    for (int c = 0; c < BM / 128; ++c)
      gl_lds16(Ab + (size_t)(c * 128 + sr) * K + kt + sc8, buf + c * 4096 + t * 8);
#pragma unroll
    for (int c = 0; c < 2; ++c)
      gl_lds16(Bb + (size_t)(c * 128 + sr) * K + kt + sc8, buf + ASZ + c * 4096 + t * 8);
  };

  STAGE(0);
  STAGE(1);
  STAGE(2);
  __builtin_amdgcn_s_waitcnt(0xF70 | (2 * L));  // tile 0 landed
  __builtin_amdgcn_s_barrier();
  asm volatile("" ::: "memory");

  for (int tt = 0; tt < NT; ++tt) {
    if (tt + 3 < NT) STAGE(tt + 3);  // buf (tt+3)&3 = buf (tt-1)&3: free since entry barrier
    const u16* buf = &lds[tt & 3][0];
#pragma unroll
    for (int ph = 0; ph < BM / 128; ++ph) {
      bf16x8 af[4], bv[4];
#pragma unroll
      for (int i = 0; i < 4; ++i)
        af[i] =
            *(const bf16x8*)(buf + (wm * (BM / 2) + (ph * 4 + i) * 16 + ll) * 32 + cb);
#pragma unroll
      for (int n = 0; n < 4; ++n)
        bv[n] = *(const bf16x8*)(buf + ASZ + (wn * 64 + n * 16 + ll) * 32 + cb);
      __builtin_amdgcn_s_setprio(1);
#pragma unroll
      for (int i = 0; i < 4; ++i)
#pragma unroll
        for (int n = 0; n < 4; ++n)
          acc[ph * 4 + i][n] = __builtin_amdgcn_mfma_f32_16x16x32_bf16(
              af[i], bv[n], acc[ph * 4 + i][n], 0, 0, 0);
      __builtin_amdgcn_s_setprio(0);
    }
    if (tt + 1 < NT) {
      if (tt + 3 < NT)
        __builtin_amdgcn_s_waitcnt(0xF70 | (2 * L));  // tt+1 landed, 2 tiles in flight
      else if (tt + 2 < NT)
        __builtin_amdgcn_s_waitcnt(0xF70 | L);
      else
        __builtin_amdgcn_s_waitcnt(0xF70);
      __builtin_amdgcn_s_barrier();
      asm volatile("" ::: "memory");
    }
  }

#pragma unroll
  for (int m = 0; m < BM / 32; ++m)
#pragma unroll
    for (int n = 0; n < 4; ++n)
#pragma unroll
      for (int j = 0; j < 4; ++j) {
        int row = tm * BM + wm * (BM / 2) + m * 16 + lh * 4 + j;
        int col = tn * 256 + wn * 64 + n * 16 + ll;
        if constexpr (EPI == 0) {
          Cf[(size_t)row * N + col] = acc[m][n][j];
        } else {
          int b = row >> 11, s = row & (S_LEN - 1);
          u16 val = f2bf(acc[m][n][j]);
          int d = col & 127;
          if (col < 2048) {
            int hh = col >> 7;
            Qo[(((size_t)b * NHEAD + hh) * S_LEN + s) * HD + d] = val;
          } else if (col < 3072) {
            int kh = (col >> 7) & 7;
            Ko[(((size_t)b * NKV + kh) * S_LEN + s) * HD + d] = val;
          } else {
            int kh = (col >> 7) & 7;
            Vo[(((size_t)b * NKV + kh) * S_LEN + s) * HD + d] = val;
          }
        }
      }
}

// ---- V [bkv][2048][128] -> Vt [bkv][128][2048] (LDS tiled transpose) ----
__global__ __launch_bounds__(256) void transpose_v(const u16* __restrict__ V,
                                                   u16* __restrict__ Vt) {
  __shared__ u16 tile[64][72];
  int id = blockIdx.x;
  int bkv = id >> 6;
  int dt = (id >> 5) & 1;
  int st = id & 31;
  const u16* Vb = V + (size_t)bkv * S_LEN * HD;
  u16* Vo = Vt + (size_t)bkv * HD * S_LEN;
  int r = threadIdx.x >> 3, c8 = (threadIdx.x & 7) * 8;
#pragma unroll
  for (int it = 0; it < 2; ++it) {
    int rr = it * 32 + r;
    *(u16x8*)(&tile[rr][c8]) =
        *(const u16x8*)(Vb + (size_t)(st * 64 + rr) * HD + dt * 64 + c8);
  }
  __syncthreads();
#pragma unroll
  for (int it = 0; it < 2; ++it) {
    int rr = it * 32 + r;
    u16x8 o;
#pragma unroll
    for (int j = 0; j < 8; ++j) o[j] = tile[c8 + j][rr];
    *(u16x8*)(Vo + (size_t)(dt * 64 + rr) * S_LEN + st * 64 + c8) = o;
  }
}

// ---------------- causal GQA flash attention (balanced pairing) ----------------
__global__ __launch_bounds__(256) void attn_fwd(const u16* __restrict__ Q,
                                                const u16* __restrict__ Kh,
                                                const u16* __restrict__ Vt,
                                                u16* __restrict__ O) {
  __shared__ __align__(16) u16 Ks[64 * 136];
  __shared__ __align__(16) u16 Vs[128 * 72];
  __shared__ __align__(16) u16 Ps[4 * 16 * 64];

  const int t = threadIdx.x;
  const int w = t >> 6, l = t & 63, lh = l >> 4, ll = l & 15;
  const int bid = blockIdx.x;
  const int swzb = (bid & 7) * 64 + (bid >> 3);
  const int bh = swzb >> 4;
  const int pair = swzb & 15;
  const int b = bh >> 4, h = bh & 15;
  const int bkv = b * NKV + (h >> 1);

  const u16* Qb = Q + (size_t)bh * S_LEN * HD;
  const u16* Kb = Kh + (size_t)bkv * S_LEN * HD;
  const u16* Vb = Vt + (size_t)bkv * HD * S_LEN;

  const int krow = t >> 4, kcol = (t & 15) * 8;
  const int vrow = t >> 3, vcol = (t & 7) * 8;

  const bf16x8 vones = {0x3F80, 0x3F80, 0x3F80, 0x3F80, 0x3F80, 0x3F80, 0x3F80, 0x3F80};

  auto loadKV = [&](int tile, u32x4 (&kr)[4], u32x4 (&vr)[4]) {
    const int kv0 = tile * 64;
#pragma unroll
    for (int p = 0; p < 4; ++p)
      kr[p] = *(const u32x4*)(Kb + (size_t)(kv0 + p * 16 + krow) * HD + kcol);
#pragma unroll
    for (int p = 0; p < 4; ++p)
      vr[p] = *(const u32x4*)(Vb + (size_t)(p * 32 + vrow) * S_LEN + kv0 + vcol);
  };
  auto storeKV = [&](u32x4 (&kr)[4], u32x4 (&vr)[4]) {
#pragma unroll
    for (int p = 0; p < 4; ++p)
      *(u32x4*)(Ks + (p * 16 + krow) * 136 + kcol) = kr[p];
#pragma unroll
    for (int p = 0; p < 4; ++p)
      *(u32x4*)(Vs + (p * 32 + vrow) * 72 + vcol) = vr[p];
  };

  for (int hf = 0; hf < 2; ++hf) {
    const int qt = hf ? (31 - pair) : pair;
    const int q0 = qt * 64;

    bf16x8 qf[4];
    const int qrow = q0 + w * 16 + ll;
#pragma unroll
    for (int c = 0; c < 4; ++c)
      qf[c] = *(const bf16x8*)(Qb + (size_t)qrow * HD + c * 32 + lh * 8);

    f32x4 accO[8] = {};
    f32x4 accL = {0.f, 0.f, 0.f, 0.f};
    float mrow[4] = {-1e30f, -1e30f, -1e30f, -1e30f};

    u32x4 kr[4], vr[4];
    loadKV(0, kr, vr);
    storeKV(kr, vr);
    __syncthreads();

    const int nt = qt + 1;
    for (int tt = 0; tt < nt; ++tt) {
      if (tt + 1 < nt) loadKV(tt + 1, kr, vr);

      f32x4 sf[4];
#pragma unroll
      for (int f = 0; f < 4; ++f) {
        sf[f] = f32x4{0.f, 0.f, 0.f, 0.f};
#pragma unroll
        for (int c = 0; c < 4; ++c) {
          bf16x8 kf = *(const bf16x8*)(Ks + (f * 16 + ll) * 136 + c * 32 + lh * 8);
          sf[f] = __builtin_amdgcn_mfma_f32_16x16x32_bf16(qf[c], kf, sf[f], 0, 0, 0);
        }
      }

      if (tt == nt - 1) {
        const int kv0 = tt * 64;
#pragma unroll
        for (int f = 0; f < 4; ++f)
#pragma unroll
          for (int j = 0; j < 4; ++j) {
            int kvg = kv0 + f * 16 + ll;
            int qg = q0 + w * 16 + lh * 4 + j;
            if (kvg > qg) sf[f][j] = -1e30f;
          }
      }

      float corr[4];
#pragma unroll
      for (int j = 0; j < 4; ++j) {
        float mx = fmaxf(fmaxf(sf[0][j], sf[1][j]), fmaxf(sf[2][j], sf[3][j]));
        mx = redmax16(mx);
        float mnew = fmaxf(mrow[j], mx);
        corr[j] = __builtin_amdgcn_exp2f(mrow[j] - mnew);
        mrow[j] = mnew;
#pragma unroll
        for (int f = 0; f < 4; ++f) sf[f][j] = __builtin_amdgcn_exp2f(sf[f][j] - mnew);
      }
#pragma unroll
      for (int n = 0; n < 8; ++n)
#pragma unroll
        for (int j = 0; j < 4; ++j) accO[n][j] *= corr[j];
#pragma unroll
      for (int j = 0; j < 4; ++j) accL[j] *= corr[j];

      char* Pw = (char*)(Ps + w * 16 * 64);
#pragma unroll
      for (int f = 0; f < 4; ++f)
#pragma unroll
        for (int j = 0; j < 4; ++j) {
          int rr = lh * 4 + j, cc = f * 16 + ll;
          unsigned bo = (unsigned)(rr * 128 + cc * 2) ^ (unsigned)((rr & 7) << 4);
          *(u16*)(Pw + bo) = f2bf(sf[f][j]);
        }

#pragma unroll
      for (int kc = 0; kc < 2; ++kc) {
        unsigned bo =
            (unsigned)(ll * 128 + (kc * 32 + lh * 8) * 2) ^ (unsigned)((ll & 7) << 4);
        bf16x8 pf = *(const bf16x8*)(Pw + bo);
#pragma unroll
        for (int n = 0; n < 8; ++n) {
          bf16x8 vf = *(const bf16x8*)(Vs + (n * 16 + ll) * 72 + kc * 32 + lh * 8);
          accO[n] = __builtin_amdgcn_mfma_f32_16x16x32_bf16(pf, vf, accO[n], 0, 0, 0);
        }
        accL = __builtin_amdgcn_mfma_f32_16x16x32_bf16(pf, vones, accL, 0, 0, 0);
      }

      __syncthreads();
      if (tt + 1 < nt) storeKV(kr, vr);
      __syncthreads();
    }

    float inv[4];
#pragma unroll
    for (int j = 0; j < 4; ++j) inv[j] = 1.0f / accL[j];
    const size_t orow = (size_t)(b * S_LEN + q0 + w * 16 + lh * 4) * 2048 + h * HD;
#pragma unroll
    for (int n = 0; n < 8; ++n)
#pragma unroll
      for (int j = 0; j < 4; ++j)
        O[orow + (size_t)j * 2048 + n * 16 + ll] = f2bf(accO[n][j] * inv[j]);
  }
}

extern "C" void kernel_launch(void* const* d_in, const int* in_sizes, int n_in,
                              void* d_out, int out_size, void* d_ws, size_t ws_size,
                              hipStream_t stream) {
  (void)in_sizes;
  (void)n_in;
  (void)out_size;
  (void)ws_size;
  const float* x = (const float*)d_in[0];
  const float* fc = (const float*)d_in[1];
  const float* fs = (const float*)d_in[2];
  const float* wq = (const float*)d_in[3];
  const float* wk = (const float*)d_in[4];
  const float* wv = (const float*)d_in[5];
  const float* wo = (const float*)d_in[6];
  float* out = (float*)d_out;

  char* ws = (char*)d_ws;
  u16* wcatT = (u16*)ws;             // [4096][2048] bf16  16.78 MB (dead after gemm<1>)
  u16* vtb = (u16*)ws;               // aliases wcatT: [16][128][2048]  8.39 MB
  u16* woT = (u16*)(ws + 16777216);  // [2048][2048]        8.39 MB
  u16* xo = (u16*)(ws + 25165824);   // x_bf16 then O      16.78 MB
  u16* qb = (u16*)(ws + 41943040);   // [32][2048][128]    16.78 MB
  u16* kb = (u16*)(ws + 58720256);   // [16][2048][128]     8.39 MB
  u16* vb = (u16*)(ws + 67108864);   // [16][2048][128]     8.39 MB
  // total 75,497,472 bytes

  conv_bf16<<<8192, 256, 0, stream>>>(x, xo, 2097152);
  transpose_w4<<<3072, 256, 0, stream>>>(wq, wk, wv, wo, wcatT, woT);

  gemm8<1, 256><<<256, 512, 0, stream>>>(xo, wcatT, nullptr, qb, kb, vb, 4096, 16);
  transpose_v<<<1024, 256, 0, stream>>>(vb, vtb);
  rope_qk<<<6144, 256, 0, stream>>>(qb, kb, fc, fs);
  attn_fwd<<<512, 256, 0, stream>>>(qb, kb, vtb, xo);
  gemm8<0, 128><<<256, 512, 0, stream>>>(xo, woT, out, nullptr, nullptr, nullptr, 2048,
                                         8);
}

// Round 5
// 233.340 us; speedup vs baseline: 2.1576x; 1.0045x over previous
//
#include <hip/hip_runtime.h>

typedef unsigned short u16;
typedef short bf16x8 __attribute__((ext_vector_type(8)));
typedef float f32x4 __attribute__((ext_vector_type(4)));
typedef unsigned int u32x4 __attribute__((ext_vector_type(4)));
typedef unsigned short u16x4 __attribute__((ext_vector_type(4)));
typedef unsigned short u16x8 __attribute__((ext_vector_type(8)));

#define S_LEN 2048
#define NHEAD 16
#define NKV 8
#define HD 128

__device__ __forceinline__ u16 f2bf(float f) {
  unsigned u = __builtin_bit_cast(unsigned, f);
  u = (u + 0x7FFFu + ((u >> 16) & 1u)) >> 16;
  return (u16)u;
}
__device__ __forceinline__ float bf2f(u16 h) {
  unsigned u = ((unsigned)h) << 16;
  return __builtin_bit_cast(float, u);
}

__device__ __forceinline__ void gl_lds16(const void* g, void* l) {
  __builtin_amdgcn_global_load_lds(
      (const __attribute__((address_space(1))) unsigned int*)g,
      (__attribute__((address_space(3))) unsigned int*)l, 16, 0, 0);
}

__device__ __forceinline__ float redmax16(float v) {
  v = fmaxf(v, __shfl_xor(v, 1));
  v = fmaxf(v, __shfl_xor(v, 2));
  v = fmaxf(v, __shfl_xor(v, 4));
  v = fmaxf(v, __shfl_xor(v, 8));
  return v;
}

// ---------------- elementwise f32 -> bf16 ----------------
__global__ __launch_bounds__(256) void conv_bf16(const float* __restrict__ in,
                                                 u16* __restrict__ out, int n4) {
  int i = blockIdx.x * 256 + threadIdx.x;
  if (i >= n4) return;
  f32x4 v = *(const f32x4*)(in + (size_t)i * 4);
  u16x4 o;
#pragma unroll
  for (int j = 0; j < 4; ++j) o[j] = f2bf(v[j]);
  *(u16x4*)(out + (size_t)i * 4) = o;
}

// ---- fused transpose of wq/wk/wv/wo: f32 [K][N] -> bf16 [roff+n][2048] ----
__global__ __launch_bounds__(256) void transpose_w4(
    const float* __restrict__ wq, const float* __restrict__ wk,
    const float* __restrict__ wv, const float* __restrict__ wo,
    u16* __restrict__ wcatT, u16* __restrict__ woT) {
  __shared__ float tile[64][65];
  int id = blockIdx.x;
  const float* in;
  u16* out;
  int N, roff, nx;
  if (id < 1024) {
    in = wq; out = wcatT; N = 2048; roff = 0; nx = 32;
  } else if (id < 1536) {
    in = wk; out = wcatT; N = 1024; roff = 2048; nx = 16; id -= 1024;
  } else if (id < 2048) {
    in = wv; out = wcatT; N = 1024; roff = 3072; nx = 16; id -= 1536;
  } else {
    in = wo; out = woT; N = 2048; roff = 0; nx = 32; id -= 2048;
  }
  int bx = id % nx;
  int by = id / nx;
  int k0 = by * 64, n0 = bx * 64;
  int tx = threadIdx.x & 63, ty = threadIdx.x >> 6;
#pragma unroll
  for (int p = 0; p < 16; ++p) {
    int r = p * 4 + ty;
    tile[r][tx] = in[(size_t)(k0 + r) * N + n0 + tx];
  }
  __syncthreads();
#pragma unroll
  for (int p = 0; p < 16; ++p) {
    int r = p * 4 + ty;
    out[(size_t)(roff + n0 + r) * 2048 + k0 + tx] = f2bf(tile[tx][r]);
  }
}

// ---------------- RoPE in-place on Q (scaled) and K ----------------
__global__ __launch_bounds__(256) void rope_qk(u16* __restrict__ q, u16* __restrict__ k,
                                               const float* __restrict__ fc,
                                               const float* __restrict__ fs) {
  const int QC = 2 * NHEAD * S_LEN * HD / 8;
  const int KC = 2 * NKV * S_LEN * HD / 8;
  int i = blockIdx.x * 256 + threadIdx.x;
  if (i >= QC + KC) return;
  u16* base;
  float scale;
  size_t e;
  if (i < QC) {
    base = q;
    e = (size_t)i * 8;
    scale = 0.12751744540368598f;  // log2(e)/sqrt(128)
  } else {
    base = k;
    e = (size_t)(i - QC) * 8;
    scale = 1.0f;
  }
  int d8 = (int)(e & 127);
  int s = (int)((e >> 7) & (S_LEN - 1));
  int dp0 = d8 >> 1;
  u16x8 v = *(const u16x8*)(base + e);
  u16x8 o;
#pragma unroll
  for (int p = 0; p < 4; ++p) {
    float xr = bf2f(v[2 * p]), xi = bf2f(v[2 * p + 1]);
    float c = fc[s * 64 + dp0 + p], sn = fs[s * 64 + dp0 + p];
    o[2 * p] = f2bf((xr * c - xi * sn) * scale);
    o[2 * p + 1] = f2bf((xr * sn + xi * c) * scale);
  }
  *(u16x8*)(base + e) = o;
}

// ===== ring-3 deep-pipelined GEMM: 128x256 tile, BK=64, counted vmcnt, =====
// ===== 8-slot XOR swizzle (zero-conflict, round-3-verified), 512 thr   =====
// EPI 0: f32 C [M][N].  EPI 1: scatter bf16 to Q/K/V head-major [b][h][s][d].
template <int EPI>
__global__ __launch_bounds__(512, 1) void gemm3r(
    const u16* __restrict__ A, const u16* __restrict__ Bt, float* __restrict__ Cf,
    u16* __restrict__ Qo, u16* __restrict__ Ko, u16* __restrict__ Vo, int N, int ntn) {
  constexpr int K = 2048, NT = K / 64;        // 32 K-tiles
  constexpr int BSZ = (128 + 256) * 64;       // u16 per ring slot (48 KB)
  __shared__ __align__(16) u16 lds[3][BSZ];   // 144 KB

  const int t = threadIdx.x;
  const int l = t & 63, lh = l >> 4, ll = l & 15;
  const int w = t >> 6, wm = w >> 2, wn = w & 3;

  const int bid = blockIdx.x;
  const int swz = (bid & 7) * (gridDim.x >> 3) + (bid >> 3);  // XCD chunk swizzle
  const int tm = swz / ntn, tn = swz % ntn;

  const u16* Ab = A + (size_t)tm * 128 * K;
  const u16* Bb = Bt + (size_t)tn * 256 * K;

  // staging: each gl_lds covers 64 rows x 64 cols (8 KB); row = c*64 + (t>>3)
  const int sr = t >> 3;                     // row within chunk (0..63)
  const int sc8 = ((t & 7) ^ (sr & 7)) * 8;  // inverse-swizzled source col (u16)

  f32x4 acc[4][4] = {};

  auto STAGE = [&](int tau) {  // 6 gl_lds instrs per wave
    const int kt = tau * 64;
    u16* buf = &lds[tau % 3][0];
#pragma unroll
    for (int c = 0; c < 2; ++c)  // A: 128 rows
      gl_lds16(Ab + (size_t)(c * 64 + sr) * K + kt + sc8, buf + c * 4096 + t * 8);
#pragma unroll
    for (int c = 0; c < 4; ++c)  // B: 256 rows
      gl_lds16(Bb + (size_t)(c * 64 + sr) * K + kt + sc8,
               buf + 8192 + c * 4096 + t * 8);
  };

  STAGE(0);
  STAGE(1);
  __builtin_amdgcn_s_waitcnt(0xF70 | 6);  // tile 0 landed, tile 1 in flight
  __builtin_amdgcn_s_barrier();
  asm volatile("" ::: "memory");

  for (int tt = 0; tt < NT; ++tt) {
    if (tt + 2 < NT) STAGE(tt + 2);  // slot (tt+2)%3: last read at tile tt-1
    const u16* bufA = &lds[tt % 3][0];
    const u16* bufB = bufA + 8192;
#pragma unroll
    for (int kk = 0; kk < 2; ++kk) {
      const int cb = ((kk * 4 + lh) ^ (ll & 7)) * 8;  // swizzled 16B slot
      bf16x8 af[4], bv[4];
#pragma unroll
      for (int m = 0; m < 4; ++m)
        af[m] = *(const bf16x8*)(bufA + (wm * 64 + m * 16 + ll) * 64 + cb);
#pragma unroll
      for (int n = 0; n < 4; ++n)
        bv[n] = *(const bf16x8*)(bufB + (wn * 64 + n * 16 + ll) * 64 + cb);
      __builtin_amdgcn_s_setprio(1);
#pragma unroll
      for (int m = 0; m < 4; ++m)
#pragma unroll
        for (int n = 0; n < 4; ++n)
          acc[m][n] =
              __builtin_amdgcn_mfma_f32_16x16x32_bf16(af[m], bv[n], acc[m][n], 0, 0, 0);
      __builtin_amdgcn_s_setprio(0);
    }
    if (tt + 1 < NT) {
      if (tt + 2 < NT)
        __builtin_amdgcn_s_waitcnt(0xF70 | 6);  // t+1 landed, t+2 in flight
      else
        __builtin_amdgcn_s_waitcnt(0xF70);      // tail: drain t+1
      __builtin_amdgcn_s_barrier();
      asm volatile("" ::: "memory");
    }
  }

#pragma unroll
  for (int m = 0; m < 4; ++m)
#pragma unroll
    for (int n = 0; n < 4; ++n)
#pragma unroll
      for (int j = 0; j < 4; ++j) {
        int row = tm * 128 + wm * 64 + m * 16 + lh * 4 + j;
        int col = tn * 256 + wn * 64 + n * 16 + ll;
        if constexpr (EPI == 0) {
          Cf[(size_t)row * N + col] = acc[m][n][j];
        } else {
          int b = row >> 11, s = row & (S_LEN - 1);
          u16 val = f2bf(acc[m][n][j]);
          int d = col & 127;
          if (col < 2048) {
            int hh = col >> 7;
            Qo[(((size_t)b * NHEAD + hh) * S_LEN + s) * HD + d] = val;
          } else if (col < 3072) {
            int kh = (col >> 7) & 7;
            Ko[(((size_t)b * NKV + kh) * S_LEN + s) * HD + d] = val;
          } else {
            int kh = (col >> 7) & 7;
            Vo[(((size_t)b * NKV + kh) * S_LEN + s) * HD + d] = val;
          }
        }
      }
}

// ---- V [bkv][2048][128] -> Vt [bkv][128][2048] (LDS tiled transpose) ----
__global__ __launch_bounds__(256) void transpose_v(const u16* __restrict__ V,
                                                   u16* __restrict__ Vt) {
  __shared__ u16 tile[64][72];
  int id = blockIdx.x;
  int bkv = id >> 6;
  int dt = (id >> 5) & 1;
  int st = id & 31;
  const u16* Vb = V + (size_t)bkv * S_LEN * HD;
  u16* Vo = Vt + (size_t)bkv * HD * S_LEN;
  int r = threadIdx.x >> 3, c8 = (threadIdx.x & 7) * 8;
#pragma unroll
  for (int it = 0; it < 2; ++it) {
    int rr = it * 32 + r;
    *(u16x8*)(&tile[rr][c8]) =
        *(const u16x8*)(Vb + (size_t)(st * 64 + rr) * HD + dt * 64 + c8);
  }
  __syncthreads();
#pragma unroll
  for (int it = 0; it < 2; ++it) {
    int rr = it * 32 + r;
    u16x8 o;
#pragma unroll
    for (int j = 0; j < 8; ++j) o[j] = tile[c8 + j][rr];
    *(u16x8*)(Vo + (size_t)(dt * 64 + rr) * S_LEN + st * 64 + c8) = o;
  }
}

// ---------------- causal GQA flash attention (balanced pairing) ----------------
__global__ __launch_bounds__(256) void attn_fwd(const u16* __restrict__ Q,
                                                const u16* __restrict__ Kh,
                                                const u16* __restrict__ Vt,
                                                u16* __restrict__ O) {
  __shared__ __align__(16) u16 Ks[64 * 136];
  __shared__ __align__(16) u16 Vs[128 * 72];
  __shared__ __align__(16) u16 Ps[4 * 16 * 64];

  const int t = threadIdx.x;
  const int w = t >> 6, l = t & 63, lh = l >> 4, ll = l & 15;
  const int bid = blockIdx.x;
  const int swzb = (bid & 7) * 64 + (bid >> 3);
  const int bh = swzb >> 4;
  const int pair = swzb & 15;
  const int b = bh >> 4, h = bh & 15;
  const int bkv = b * NKV + (h >> 1);

  const u16* Qb = Q + (size_t)bh * S_LEN * HD;
  const u16* Kb = Kh + (size_t)bkv * S_LEN * HD;
  const u16* Vb = Vt + (size_t)bkv * HD * S_LEN;

  const int krow = t >> 4, kcol = (t & 15) * 8;
  const int vrow = t >> 3, vcol = (t & 7) * 8;

  const bf16x8 vones = {0x3F80, 0x3F80, 0x3F80, 0x3F80, 0x3F80, 0x3F80, 0x3F80, 0x3F80};

  auto loadKV = [&](int tile, u32x4 (&kr)[4], u32x4 (&vr)[4]) {
    const int kv0 = tile * 64;
#pragma unroll
    for (int p = 0; p < 4; ++p)
      kr[p] = *(const u32x4*)(Kb + (size_t)(kv0 + p * 16 + krow) * HD + kcol);
#pragma unroll
    for (int p = 0; p < 4; ++p)
      vr[p] = *(const u32x4*)(Vb + (size_t)(p * 32 + vrow) * S_LEN + kv0 + vcol);
  };
  auto storeKV = [&](u32x4 (&kr)[4], u32x4 (&vr)[4]) {
#pragma unroll
    for (int p = 0; p < 4; ++p)
      *(u32x4*)(Ks + (p * 16 + krow) * 136 + kcol) = kr[p];
#pragma unroll
    for (int p = 0; p < 4; ++p)
      *(u32x4*)(Vs + (p * 32 + vrow) * 72 + vcol) = vr[p];
  };

  for (int hf = 0; hf < 2; ++hf) {
    const int qt = hf ? (31 - pair) : pair;
    const int q0 = qt * 64;

    bf16x8 qf[4];
    const int qrow = q0 + w * 16 + ll;
#pragma unroll
    for (int c = 0; c < 4; ++c)
      qf[c] = *(const bf16x8*)(Qb + (size_t)qrow * HD + c * 32 + lh * 8);

    f32x4 accO[8] = {};
    f32x4 accL = {0.f, 0.f, 0.f, 0.f};
    float mrow[4] = {-1e30f, -1e30f, -1e30f, -1e30f};

    u32x4 kr[4], vr[4];
    loadKV(0, kr, vr);
    storeKV(kr, vr);
    __syncthreads();

    const int nt = qt + 1;
    for (int tt = 0; tt < nt; ++tt) {
      if (tt + 1 < nt) loadKV(tt + 1, kr, vr);

      f32x4 sf[4];
#pragma unroll
      for (int f = 0; f < 4; ++f) {
        sf[f] = f32x4{0.f, 0.f, 0.f, 0.f};
#pragma unroll
        for (int c = 0; c < 4; ++c) {
          bf16x8 kf = *(const bf16x8*)(Ks + (f * 16 + ll) * 136 + c * 32 + lh * 8);
          sf[f] = __builtin_amdgcn_mfma_f32_16x16x32_bf16(qf[c], kf, sf[f], 0, 0, 0);
        }
      }

      if (tt == nt - 1) {
        const int kv0 = tt * 64;
#pragma unroll
        for (int f = 0; f < 4; ++f)
#pragma unroll
          for (int j = 0; j < 4; ++j) {
            int kvg = kv0 + f * 16 + ll;
            int qg = q0 + w * 16 + lh * 4 + j;
            if (kvg > qg) sf[f][j] = -1e30f;
          }
      }

      float corr[4];
#pragma unroll
      for (int j = 0; j < 4; ++j) {
        float mx = fmaxf(fmaxf(sf[0][j], sf[1][j]), fmaxf(sf[2][j], sf[3][j]));
        mx = redmax16(mx);
        float mnew = fmaxf(mrow[j], mx);
        corr[j] = __builtin_amdgcn_exp2f(mrow[j] - mnew);
        mrow[j] = mnew;
#pragma unroll
        for (int f = 0; f < 4; ++f) sf[f][j] = __builtin_amdgcn_exp2f(sf[f][j] - mnew);
      }
#pragma unroll
      for (int n = 0; n < 8; ++n)
#pragma unroll
        for (int j = 0; j < 4; ++j) accO[n][j] *= corr[j];
#pragma unroll
      for (int j = 0; j < 4; ++j) accL[j] *= corr[j];

      char* Pw = (char*)(Ps + w * 16 * 64);
#pragma unroll
      for (int f = 0; f < 4; ++f)
#pragma unroll
        for (int j = 0; j < 4; ++j) {
          int rr = lh * 4 + j, cc = f * 16 + ll;
          unsigned bo = (unsigned)(rr * 128 + cc * 2) ^ (unsigned)((rr & 7) << 4);
          *(u16*)(Pw + bo) = f2bf(sf[f][j]);
        }

#pragma unroll
      for (int kc = 0; kc < 2; ++kc) {
        unsigned bo =
            (unsigned)(ll * 128 + (kc * 32 + lh * 8) * 2) ^ (unsigned)((ll & 7) << 4);
        bf16x8 pf = *(const bf16x8*)(Pw + bo);
#pragma unroll
        for (int n = 0; n < 8; ++n) {
          bf16x8 vf = *(const bf16x8*)(Vs + (n * 16 + ll) * 72 + kc * 32 + lh * 8);
          accO[n] = __builtin_amdgcn_mfma_f32_16x16x32_bf16(pf, vf, accO[n], 0, 0, 0);
        }
        accL = __builtin_amdgcn_mfma_f32_16x16x32_bf16(pf, vones, accL, 0, 0, 0);
      }

      __syncthreads();
      if (tt + 1 < nt) storeKV(kr, vr);
      __syncthreads();
    }

    float inv[4];
#pragma unroll
    for (int j = 0; j < 4; ++j) inv[j] = 1.0f / accL[j];
    const size_t orow = (size_t)(b * S_LEN + q0 + w * 16 + lh * 4) * 2048 + h * HD;
#pragma unroll
    for (int n = 0; n < 8; ++n)
#pragma unroll
      for (int j = 0; j < 4; ++j)
        O[orow + (size_t)j * 2048 + n * 16 + ll] = f2bf(accO[n][j] * inv[j]);
  }
}

extern "C" void kernel_launch(void* const* d_in, const int* in_sizes, int n_in,
                              void* d_out, int out_size, void* d_ws, size_t ws_size,
                              hipStream_t stream) {
  (void)in_sizes;
  (void)n_in;
  (void)out_size;
  (void)ws_size;
  const float* x = (const float*)d_in[0];
  const float* fc = (const float*)d_in[1];
  const float* fs = (const float*)d_in[2];
  const float* wq = (const float*)d_in[3];
  const float* wk = (const float*)d_in[4];
  const float* wv = (const float*)d_in[5];
  const float* wo = (const float*)d_in[6];
  float* out = (float*)d_out;

  char* ws = (char*)d_ws;
  u16* wcatT = (u16*)ws;             // [4096][2048] bf16  16.78 MB (dead after gemm<1>)
  u16* vtb = (u16*)ws;               // aliases wcatT: [16][128][2048]  8.39 MB
  u16* woT = (u16*)(ws + 16777216);  // [2048][2048]        8.39 MB
  u16* xo = (u16*)(ws + 25165824);   // x_bf16 then O      16.78 MB
  u16* qb = (u16*)(ws + 41943040);   // [32][2048][128]    16.78 MB
  u16* kb = (u16*)(ws + 58720256);   // [16][2048][128]     8.39 MB
  u16* vb = (u16*)(ws + 67108864);   // [16][2048][128]     8.39 MB
  // total 75,497,472 bytes

  conv_bf16<<<8192, 256, 0, stream>>>(x, xo, 2097152);
  transpose_w4<<<3072, 256, 0, stream>>>(wq, wk, wv, wo, wcatT, woT);

  gemm3r<1><<<512, 512, 0, stream>>>(xo, wcatT, nullptr, qb, kb, vb, 4096, 16);
  transpose_v<<<1024, 256, 0, stream>>>(vb, vtb);
  rope_qk<<<6144, 256, 0, stream>>>(qb, kb, fc, fs);
  attn_fwd<<<512, 256, 0, stream>>>(qb, kb, vtb, xo);
  gemm3r<0><<<256, 512, 0, stream>>>(xo, woT, out, nullptr, nullptr, nullptr, 2048, 8);
}